// Round 8
// baseline (960.889 us; speedup 1.0000x reference)
//
#include <hip/hip_runtime.h>
#include <math.h>
#include <stdint.h>

// Problem dims
#define NB 16384    // batch
#define NH 768      // hidden
#define ND 784      // input features
#define NC 10       // classes
#define NW 12       // u64 words per 768-bit row

typedef float v2f __attribute__((ext_vector_type(2)));

// v_pk_fma_f32: D.lo = fma(S0.lo,S1.lo,S2.lo), D.hi = fma(S0.hi,S1.hi,S2.hi)
// Each half is a single-rounded IEEE f32 fma == __fmaf_rn -> bit-identical math.
__device__ __forceinline__ v2f pkfma(v2f s0, v2f s1, v2f s2) {
    asm("v_pk_fma_f32 %0, %1, %2, %0" : "+v"(s2) : "v"(s0), "v"(s1));
    return s2;
}

// ---------------------------------------------------------------------------
// prep: BN params in FAITHFUL f32 (replicating np op-by-op):
// sc = g * (1 / sqrt(v + 1e-5)), each op f32-rounded. [0]=sc,[1]=m,[2]=be,[3]=bias
// ---------------------------------------------------------------------------
__global__ void k_bnprep_f32(const float* __restrict__ g, const float* __restrict__ be,
                             const float* __restrict__ m, const float* __restrict__ v,
                             const float* __restrict__ bias, float* __restrict__ out) {
    int i = blockIdx.x * 256 + threadIdx.x;
    if (i >= NH) return;
    float t1 = __fadd_rn(v[i], 1e-5f);
    float t2 = __fsqrt_rn(t1);
    float t3 = __fdiv_rn(1.0f, t2);
    out[i]          = __fmul_rn(g[i], t3);
    out[NH + i]     = m[i];
    out[2 * NH + i] = be[i];
    out[3 * NH + i] = bias[i];
}

// ---------------------------------------------------------------------------
// prep: W1 signs as bf16 +/-1 bit patterns (0x3F80 / 0xBF80), row-major [col][k]
// ---------------------------------------------------------------------------
__global__ void k_pack_w1bf(const float* __restrict__ W1, unsigned short* __restrict__ wbf) {
    int k = blockIdx.x * 256 + threadIdx.x;
    int col = blockIdx.y;
    if (k >= ND) return;
    float v = W1[(size_t)col * ND + k];
    wbf[(size_t)col * ND + k] = (v >= 0.0f) ? (unsigned short)0x3F80 : (unsigned short)0xBF80;
}

// ---------------------------------------------------------------------------
// prep: W2/W3 sign bits, transposed words: wT[j*768 + col] bit l = (W[col][j*64+l] >= 0)
// ---------------------------------------------------------------------------
__global__ void k_pack_wT(const float* __restrict__ W, unsigned long long* __restrict__ wT) {
    int idx = blockIdx.x * 256 + threadIdx.x;
    if (idx >= NH * NW) return;
    int col = idx / NW, j = idx % NW;
    unsigned long long w = 0ull;
    for (int l = 0; l < 64; ++l) {
        float v = W[(size_t)col * NH + j * 64 + l];
        w |= (unsigned long long)(v >= 0.0f ? 1 : 0) << l;
    }
    wT[(size_t)j * NH + col] = w;
}

// ---------------------------------------------------------------------------
// GEMM1 replicating numpy einsum sum_of_products_contig_two (AVX512 npyv).
// Chain structure IDENTICAL to R9/R17 (bit-exact s1): per (row,col) chain
// (g,i) accumulates k = t*64 + g*16 + (jh*8+i), t=0..11 ascending, tail
// k=768.. into g=0; combine (a0+a1)+(a2+a3); pair-sum shfl_xor(32); tree
// 8/4/2/1; BN f32 op-by-op; ballot -> sign bits.
// R18 vs R17 (R9-parity): LDS-PIPE is the bottleneck (derived from m134
// costs: w-reads 12cyc + x-broadcasts 4cyc ~ 31k cyc/CU/round vs VALU 13k;
// VALUBusy 66% = VALU hiding under LDS). Two changes:
//  1) TWO rows per wave (w-read amortized 2x): 49x12 + 196x4 = 1372 cyc
//     per 2-row-tile vs 2x980 = 0.70x LDS time. Read GEOMETRY unchanged
//     (same per-lane addresses as R9: 0 conflicts; y-reads broadcast like x).
//  2) v_pk_fma_f32 (2 single-rounded IEEE f32 FMA/instr -> bit-identical):
//     per 16 MACs = 8 unpack + 8 pk_fma = 1.0 VALU/MAC (R9 2.13) -> VALU
//     busy ~250us, stays hidden under LDS.
// Spill-proofing (R10/R11/R14 post-mortems): 256-thr block + launch_bounds
// (256,2) -> VGPR cap 256 (measured semantics: min-BLOCKS/CU; cap =
// 512/(blocks*waves/4SIMD)); live ~120. Accs = v2f arrays, static indices
// only; full unroll (R16: unroll-1 serializes, 850us).
// Block: 256 thr = 4 waves; wave w = rows {2w, 2w+1}, 32 cols x 2 jh per
// lane split; 2 tiles (64 cols). LDS 76,800 B -> 2 blocks/CU (8 waves).
// grid (NB/8, NH/64).
// ---------------------------------------------------------------------------
__global__ __launch_bounds__(256, 2)
void k_gemm1_pk(const float* __restrict__ x, const unsigned short* __restrict__ wbf,
                const float* __restrict__ bnp, unsigned int* __restrict__ s1p32) {
    __shared__ float xs[8][ND];                         // 25,088 B
    __shared__ alignas(16) unsigned short wl[32][808];  // 51,712 B (pitch 1616 B)

    const int tid = threadIdx.x;
    const int wave = tid >> 6, lane = tid & 63;
    const int colsub = lane & 31, jh = lane >> 5;
    const int j0 = jh * 8;
    const int rA = 2 * wave;
    const int r0 = blockIdx.x * 8;

    // stage x: wave stages its OWN two rows (self-use only: same-wave lgkm
    // ordering suffices; reads start after the w-barrier anyway)
    {
        const float4* s0 = (const float4*)(x + (size_t)(r0 + rA) * ND);
        const float4* s1 = (const float4*)(x + (size_t)(r0 + rA + 1) * ND);
        float4* d0 = (float4*)&xs[rA][0];
        float4* d1 = (float4*)&xs[rA + 1][0];
        for (int k4 = lane; k4 < 196; k4 += 64) d0[k4] = s0[k4];
        for (int k4 = lane; k4 < 196; k4 += 64) d1[k4] = s1[k4];
    }

    const float* xr0 = &xs[rA][j0];
    const float* xr1 = &xs[rA + 1][j0];

#pragma unroll 1
    for (int tile = 0; tile < 2; ++tile) {
        const int c0 = blockIdx.y * 64 + tile * 32;
        __syncthreads();   // tile1: all waves done reading wl tile0
        // stage w: 32 cols x 98 uint4 per col; 8 threads per col
        {
            int c = tid >> 3, q0 = tid & 7;
            uint4* dst = (uint4*)&wl[c][0];
            const uint4* srcp = (const uint4*)(wbf + (size_t)(c0 + c) * ND);
            for (int q = q0; q < 98; q += 8) dst[q] = srcp[q];
        }
        __syncthreads();

        const unsigned short* wrow = &wl[colsub][j0];

        v2f a0[4][4], a1[4][4];
#pragma unroll
        for (int g = 0; g < 4; ++g)
#pragma unroll
            for (int p = 0; p < 4; ++p) { a0[g][p] = (v2f){0.f, 0.f}; a1[g][p] = (v2f){0.f, 0.f}; }

        // main loop: t = 0..11, each covers k = t*64 .. t*64+63
#pragma unroll
        for (int t = 0; t < 12; ++t) {
#pragma unroll
            for (int g = 0; g < 4; ++g) {
                const int kk = t * 64 + g * 16;
                uint4 wA = *(const uint4*)(wrow + kk);       // 8 bf16: k = kk+j0..+7
                float4 x0 = *(const float4*)(xr0 + kk);
                float4 x1 = *(const float4*)(xr0 + kk + 4);
                float4 y0 = *(const float4*)(xr1 + kk);
                float4 y1 = *(const float4*)(xr1 + kk + 4);
                unsigned int dw[4] = {wA.x, wA.y, wA.z, wA.w};
                v2f wp[4];
#pragma unroll
                for (int p = 0; p < 4; ++p) {
                    wp[p].x = __uint_as_float(dw[p] << 16);          // even k (lo bf16)
                    wp[p].y = __uint_as_float(dw[p] & 0xFFFF0000u);  // odd  k (hi bf16)
                }
                a0[g][0] = pkfma(wp[0], (v2f){x0.x, x0.y}, a0[g][0]);
                a0[g][1] = pkfma(wp[1], (v2f){x0.z, x0.w}, a0[g][1]);
                a0[g][2] = pkfma(wp[2], (v2f){x1.x, x1.y}, a0[g][2]);
                a0[g][3] = pkfma(wp[3], (v2f){x1.z, x1.w}, a0[g][3]);
                a1[g][0] = pkfma(wp[0], (v2f){y0.x, y0.y}, a1[g][0]);
                a1[g][1] = pkfma(wp[1], (v2f){y0.z, y0.w}, a1[g][1]);
                a1[g][2] = pkfma(wp[2], (v2f){y1.x, y1.y}, a1[g][2]);
                a1[g][3] = pkfma(wp[3], (v2f){y1.z, y1.w}, a1[g][3]);
            }
        }
        // single-vector tail: k = 768..783 into group 0
        {
            const int kk = 768;
            uint4 wA = *(const uint4*)(wrow + kk);
            float4 x0 = *(const float4*)(xr0 + kk);
            float4 x1 = *(const float4*)(xr0 + kk + 4);
            float4 y0 = *(const float4*)(xr1 + kk);
            float4 y1 = *(const float4*)(xr1 + kk + 4);
            unsigned int dw[4] = {wA.x, wA.y, wA.z, wA.w};
            v2f wp[4];
#pragma unroll
            for (int p = 0; p < 4; ++p) {
                wp[p].x = __uint_as_float(dw[p] << 16);
                wp[p].y = __uint_as_float(dw[p] & 0xFFFF0000u);
            }
            a0[0][0] = pkfma(wp[0], (v2f){x0.x, x0.y}, a0[0][0]);
            a0[0][1] = pkfma(wp[1], (v2f){x0.z, x0.w}, a0[0][1]);
            a0[0][2] = pkfma(wp[2], (v2f){x1.x, x1.y}, a0[0][2]);
            a0[0][3] = pkfma(wp[3], (v2f){x1.z, x1.w}, a0[0][3]);
            a1[0][0] = pkfma(wp[0], (v2f){y0.x, y0.y}, a1[0][0]);
            a1[0][1] = pkfma(wp[1], (v2f){y0.z, y0.w}, a1[0][1]);
            a1[0][2] = pkfma(wp[2], (v2f){y1.x, y1.y}, a1[0][2]);
            a1[0][3] = pkfma(wp[3], (v2f){y1.z, y1.w}, a1[0][3]);
        }

        // -------- combine + epilogue (exact R9 op sequence), rows rA, rA+1 --------
        const int col = c0 + colsub;
        const float sc = bnp[col], mm = bnp[NH + col], be = bnp[2 * NH + col],
                    bias = bnp[3 * NH + col];

#define COMB_EPI_PK(A, RIDX)                                                   \
        {                                                                      \
            float v_[8];                                                       \
            _Pragma("unroll")                                                  \
            for (int p = 0; p < 4; ++p) {                                      \
                v_[2 * p] = __fadd_rn(__fadd_rn(A[0][p].x, A[1][p].x),         \
                                      __fadd_rn(A[2][p].x, A[3][p].x));        \
                v_[2 * p + 1] = __fadd_rn(__fadd_rn(A[0][p].y, A[1][p].y),     \
                                          __fadd_rn(A[2][p].y, A[3][p].y));    \
            }                                                                  \
            float h8[8];                                                       \
            _Pragma("unroll")                                                  \
            for (int i = 0; i < 8; ++i) {                                      \
                float o = __shfl_xor(v_[i], 32, 64);                           \
                h8[i] = __fadd_rn(v_[i], o);                                   \
            }                                                                  \
            float h4[4], h2[2];                                                \
            _Pragma("unroll")                                                  \
            for (int i = 0; i < 4; ++i) h4[i] = __fadd_rn(h8[i], h8[i + 4]);   \
            _Pragma("unroll")                                                  \
            for (int i = 0; i < 2; ++i) h2[i] = __fadd_rn(h4[i], h4[i + 2]);   \
            float acc = __fadd_rn(h2[0], h2[1]);                               \
            float h  = __fadd_rn(acc, bias);                                   \
            float t1 = __fsub_rn(h, mm);                                       \
            float u  = __fmul_rn(t1, sc);                                      \
            float hb = __fadd_rn(u, be);                                       \
            unsigned long long word = __ballot(hb >= 0.0f);                    \
            if (lane == 0)                                                     \
                s1p32[(size_t)(r0 + rA + (RIDX)) * (2 * NW) +                  \
                      blockIdx.y * 2 + tile] = (unsigned int)word;             \
        }

        COMB_EPI_PK(a0, 0)
        COMB_EPI_PK(a1, 1)
#undef COMB_EPI_PK
    }
}

// ---------------------------------------------------------------------------
// Binary layers 2/3: dot = 768 - 2*popcount(a XOR w) — exact integer, matches
// any-order f32 evaluation of +/-1 GEMM bit-for-bit (all partials exact).
// Epilogue faithful f32: h = fl(dot + b), BN op-by-op.
// MODE 0: sign -> packed bits. MODE 1: hardtanh -> f32 out.
// ---------------------------------------------------------------------------
template <int MODE>
__global__ __launch_bounds__(256, 2)
void k_popbin(const unsigned long long* __restrict__ Ap,
              const unsigned long long* __restrict__ wT,
              const float* __restrict__ bnp,
              unsigned long long* __restrict__ Sp, float* __restrict__ h_out) {
    __shared__ unsigned long long as[64][NW];
    const int tid = threadIdx.x;
    const int b0 = blockIdx.x * 64;

    {
        unsigned long long* asf = &as[0][0];
        const unsigned long long* src = Ap + (size_t)b0 * NW;
        for (int i = tid; i < 64 * NW; i += 256) asf[i] = src[i];
    }
    __syncthreads();

    const int wave = tid >> 6, lane = tid & 63;

    for (int chunk = 0; chunk < NW; ++chunk) {
        const int col = chunk * 64 + lane;
        unsigned long long w[NW];
#pragma unroll
        for (int j = 0; j < NW; ++j) w[j] = wT[(size_t)j * NH + col];
        const float sc = bnp[col], mm = bnp[NH + col], be = bnp[2 * NH + col],
                    bias = bnp[3 * NH + col];
        for (int r = 0; r < 16; ++r) {
            const int row = wave * 16 + r;
            int d = 0;
#pragma unroll
            for (int j = 0; j < NW; ++j)
                d += __builtin_popcountll(as[row][j] ^ w[j]);
            int dot = NH - 2 * d;
            float h  = __fadd_rn((float)dot, bias);
            float t  = __fsub_rn(h, mm);
            float u  = __fmul_rn(t, sc);
            float hb = __fadd_rn(u, be);
            if (MODE == 0) {
                unsigned long long word = __ballot(hb >= 0.0f);
                if (lane == 0) Sp[(size_t)(b0 + row) * NW + chunk] = word;
            } else {
                float hc = fminf(fmaxf(hb, -1.0f), 1.0f);
                h_out[(size_t)(b0 + row) * NH + col] = hc;
            }
        }
    }
}

// ---------------------------------------------------------------------------
// fc4 + log_softmax: one wave per row, double accumulation + shuffle reduce
// ---------------------------------------------------------------------------
__global__ __launch_bounds__(256, 4)
void k_fc4(const float* __restrict__ h3, const float* __restrict__ W4,
           const float* __restrict__ b4, float* __restrict__ out) {
    __shared__ float w4s[NC * NH];
    const int tid = threadIdx.x;
    for (int i = tid; i < NC * NH; i += 256) w4s[i] = W4[i];
    __syncthreads();

    const int wave = tid >> 6, lane = tid & 63;
    const int row = blockIdx.x * 4 + wave;
    const float* hrow = h3 + (size_t)row * NH;

    double p[NC];
#pragma unroll
    for (int c = 0; c < NC; ++c) p[c] = 0.0;

    for (int it = 0; it < NH / 64; ++it) {
        int j = it * 64 + lane;
        double hv = (double)hrow[j];
#pragma unroll
        for (int c = 0; c < NC; ++c) p[c] += hv * (double)w4s[c * NH + j];
    }
#pragma unroll
    for (int c = 0; c < NC; ++c) {
#pragma unroll
        for (int off = 32; off > 0; off >>= 1) p[c] += __shfl_xor(p[c], off, 64);
    }
    double lg[NC];
    double mx = -1e300;
#pragma unroll
    for (int c = 0; c < NC; ++c) {
        lg[c] = p[c] + (double)b4[c];
        mx = fmax(mx, lg[c]);
    }
    double s = 0.0;
#pragma unroll
    for (int c = 0; c < NC; ++c) s += exp(lg[c] - mx);
    double lse = mx + log(s);
    if (lane < NC) {
        double v = 0.0;
#pragma unroll
        for (int c = 0; c < NC; ++c)
            if (lane == c) v = lg[c];
        out[(size_t)row * NC + lane] = (float)(v - lse);
    }
}

// ---------------------------------------------------------------------------
// launch
// ---------------------------------------------------------------------------
extern "C" void kernel_launch(void* const* d_in, const int* in_sizes, int n_in,
                              void* d_out, int out_size, void* d_ws, size_t ws_size,
                              hipStream_t stream) {
    const float* x  = (const float*)d_in[0];
    const float* W1 = (const float*)d_in[1];
    const float* b1 = (const float*)d_in[2];
    const float* W2 = (const float*)d_in[3];
    const float* b2 = (const float*)d_in[4];
    const float* W3 = (const float*)d_in[5];
    const float* b3 = (const float*)d_in[6];
    const float* W4 = (const float*)d_in[7];
    const float* b4 = (const float*)d_in[8];
    const float* g1 = (const float*)d_in[9],  *be1 = (const float*)d_in[10];
    const float* m1 = (const float*)d_in[11], *v1  = (const float*)d_in[12];
    const float* g2 = (const float*)d_in[13], *be2 = (const float*)d_in[14];
    const float* m2 = (const float*)d_in[15], *v2  = (const float*)d_in[16];
    const float* g3 = (const float*)d_in[17], *be3 = (const float*)d_in[18];
    const float* m3 = (const float*)d_in[19], *v3  = (const float*)d_in[20];
    float* out = (float*)d_out;

    char* ws = (char*)d_ws;
    size_t off = 0;
    unsigned short* wbf = (unsigned short*)(ws + off);  off += (size_t)NH * ND * 2;   // 1,204,224
    unsigned long long* w2pT = (unsigned long long*)(ws + off); off += (size_t)NW * NH * 8;
    unsigned long long* w3pT = (unsigned long long*)(ws + off); off += (size_t)NW * NH * 8;
    unsigned long long* s1p  = (unsigned long long*)(ws + off); off += (size_t)NB * NW * 8;
    unsigned long long* s2p  = (unsigned long long*)(ws + off); off += (size_t)NB * NW * 8;
    float*  h3   = (float*)(ws + off);              off += (size_t)NB * NH * 4;
    float* bnp1 = (float*)(ws + off);               off += (size_t)4 * NH * 4;
    float* bnp2 = (float*)(ws + off);               off += (size_t)4 * NH * 4;
    float* bnp3 = (float*)(ws + off);               off += (size_t)4 * NH * 4;
    (void)ws_size; (void)in_sizes; (void)n_in; (void)out_size;

    // prep
    k_pack_w1bf<<<dim3(4, NH), 256, 0, stream>>>(W1, wbf);
    k_pack_wT<<<dim3((NH * NW + 255) / 256), 256, 0, stream>>>(W2, w2pT);
    k_pack_wT<<<dim3((NH * NW + 255) / 256), 256, 0, stream>>>(W3, w3pT);
    k_bnprep_f32<<<dim3(3), 256, 0, stream>>>(g1, be1, m1, v1, b1, bnp1);
    k_bnprep_f32<<<dim3(3), 256, 0, stream>>>(g2, be2, m2, v2, b2, bnp2);
    k_bnprep_f32<<<dim3(3), 256, 0, stream>>>(g3, be3, m3, v3, b3, bnp3);

    // layers
    k_gemm1_pk<<<dim3(NB / 8, NH / 64), 256, 0, stream>>>(x, wbf, bnp1,
                                                          (unsigned int*)s1p);
    k_popbin<0><<<dim3(NB / 64), 256, 0, stream>>>(s1p, w2pT, bnp2, s2p, nullptr);
    k_popbin<1><<<dim3(NB / 64), 256, 0, stream>>>(s2p, w3pT, bnp3, nullptr, h3);
    k_fc4<<<dim3(NB / 4), 256, 0, stream>>>(h3, W4, b4, out);
}